// Round 9
// baseline (473.583 us; speedup 1.0000x reference)
//
#include <hip/hip_runtime.h>
#include <cfloat>

#define NROWS 65536
#define DIM   256
#define KCB   4096

typedef __attribute__((ext_vector_type(8))) short bf16x8;
typedef __attribute__((ext_vector_type(4))) float f32x4;
typedef unsigned short ushort;
typedef unsigned int uint;

// ws layout (bytes):
//   [0,       16384)   : cref    float[4096]    (numpy-exact column sums of v^2)
//   [32768,   1081344) : int4    cand[65536]    (top-4 candidates per row)
//   [1081344, 1146880) : float   partial[1024]  (per-emuquant-block loss partials)
//   [1343488, 5537792) : vt      float[4096*256]  (transposed codebook, fp32)
//   [5537792, 7634944) : vthp    ushort[4096*256] (codebook, MFMA-fragment-packed bf16)

__device__ __forceinline__ bool better(float v1, int i1, float v2, int i2) {
    return (v1 < v2) || (v1 == v2 && i1 < i2);
}

// launder through a VGPR so hipcc cannot FMA-contract or reassociate
__device__ __forceinline__ float opaque(float x) {
    asm volatile("" : "+v"(x));
    return x;
}

__device__ __forceinline__ ushort f2bf(float f) {   // RNE fp32 -> bf16
    uint u = __float_as_uint(f);
    return (ushort)((u + 0x7FFFu + ((u >> 16) & 1u)) >> 16);
}

// lexicographic top-4 insert (for merges)
__device__ __forceinline__ void insert4b(float v[4], int idx[4], float s, int k) {
    if (better(s, k, v[3], idx[3])) {
        if (better(s, k, v[2], idx[2])) {
            v[3] = v[2]; idx[3] = idx[2];
            if (better(s, k, v[1], idx[1])) {
                v[2] = v[1]; idx[2] = idx[1];
                if (better(s, k, v[0], idx[0])) {
                    v[1] = v[0]; idx[1] = idx[0]; v[0] = s; idx[0] = k;
                } else { v[1] = s; idx[1] = k; }
            } else { v[2] = s; idx[2] = k; }
        } else { v[3] = s; idx[3] = k; }
    }
}

// ---------- kernel 1a: numpy-exact C_k = sequential sum_d fl(v[d][k]^2) --------
__global__ void vq_cref_kernel(const float* __restrict__ v,
                               float* __restrict__ cref) {
    int k = blockIdx.x * blockDim.x + threadIdx.x;
    float t = v[k];
    float c = opaque(t * t);
    #pragma unroll 8
    for (int d = 1; d < DIM; ++d) {
        t = v[d * KCB + k];
        c = c + opaque(t * t);
    }
    cref[k] = c;
}

// ---------- kernel 1b: transpose V (D,K) -> vt fp32 (K,D) ---------------------
__global__ void vq_transpose_kernel(const float* __restrict__ v,
                                    float* __restrict__ vt) {
    __shared__ float tile[32][33];
    int d0 = blockIdx.x * 32;
    int k0 = blockIdx.y * 32;
    int tx = threadIdx.x;
    int ty = threadIdx.y;
    #pragma unroll
    for (int i = 0; i < 32; i += 8)
        tile[ty + i][tx] = v[(d0 + ty + i) * KCB + k0 + tx];
    __syncthreads();
    #pragma unroll
    for (int i = 0; i < 32; i += 8)
        vt[(k0 + ty + i) * DIM + d0 + tx] = tile[tx][ty + i];
}

// ---------- kernel 1c: pack vt -> vthp in MFMA-fragment order ------------------
// Fragment f = (g*8 + dt)*64 + lane  holds bf16x8 = row (g*16 + (lane&15)),
// dims [(dt*4 + (lane>>4))*8, +8).  af loads become contiguous 1 KB bursts.
__global__ __launch_bounds__(256) void vq_pack_kernel(const float* __restrict__ vt,
                                                      ushort* __restrict__ vthp) {
    int t = blockIdx.x * 256 + threadIdx.x;   // 0..131071
    int lane = t & 63;
    int dt   = (t >> 6) & 7;
    int g    = t >> 9;                        // row-group 0..255
    int row  = g * 16 + (lane & 15);
    int dbase = (dt * 4 + (lane >> 4)) * 8;
    const float* src = vt + (size_t)row * DIM + dbase;
    float4 f0 = *(const float4*)src;
    float4 f1 = *(const float4*)(src + 4);
    int4 p;
    p.x = (int)f2bf(f0.x) | ((int)f2bf(f0.y) << 16);
    p.y = (int)f2bf(f0.z) | ((int)f2bf(f0.w) << 16);
    p.z = (int)f2bf(f1.x) | ((int)f2bf(f1.y) << 16);
    p.w = (int)f2bf(f1.z) | ((int)f2bf(f1.w) << 16);
    *(int4*)(vthp + (size_t)t * 8) = p;
}

// ---------- kernel 2: bf16 MFMA + branchless packed top-2 argmin ---------------
// Measured-optimal config: 64 rows/block, 4 blocks/CU, fragment-packed af.
__global__ __launch_bounds__(256, 4) void vq_mfma_argmin_kernel(
        const float* __restrict__ x, const ushort* __restrict__ vthp,
        const float* __restrict__ cref, int4* __restrict__ cand) {
    // Bk[u][r][8]: unit u = 8 bf16 of dims [u*8,u*8+8), r = x-row; reused as mbuf
    __shared__ __align__(16) ushort Bk[32 * 64 * 8];      // 32 KB

    const int tid  = threadIdx.x;
    const int w    = tid >> 6;        // wave 0..3
    const int lane = tid & 63;
    const int l15  = lane & 15;
    const int quad = lane >> 4;
    const int row0 = blockIdx.x * 64;

    // ---- stage x-tile once: 64 rows x 256 dims -> bf16, k-major ----
    {
        const int r_ = tid >> 2;
        const int q_ = tid & 3;
        const float* xs = &x[(size_t)(row0 + r_) * DIM + q_ * 64];
        #pragma unroll
        for (int i = 0; i < 8; ++i) {
            float4 f0 = *(const float4*)(xs + i * 8);
            float4 f1 = *(const float4*)(xs + i * 8 + 4);
            int4 p;
            p.x = (int)f2bf(f0.x) | ((int)f2bf(f0.y) << 16);
            p.y = (int)f2bf(f0.z) | ((int)f2bf(f0.w) << 16);
            p.z = (int)f2bf(f1.x) | ((int)f2bf(f1.y) << 16);
            p.w = (int)f2bf(f1.z) | ((int)f2bf(f1.w) << 16);
            int u = q_ * 8 + i;
            *(int4*)&Bk[(u * 64 + r_) * 8] = p;
        }
    }
    __syncthreads();

    // per-lane packed top-2 per nj: score with 8-bit local id in mantissa LSBs
    float m0[4], m1[4];
    #pragma unroll
    for (int nj = 0; nj < 4; ++nj) { m0[nj] = FLT_MAX; m1[nj] = FLT_MAX; }

    for (int kt = 0; kt < 16; ++kt) {
        f32x4 acc[4][4];
        #pragma unroll
        for (int mi = 0; mi < 4; ++mi)
            #pragma unroll
            for (int nj = 0; nj < 4; ++nj)
                acc[mi][nj] = (f32x4)0.f;

        // fragment base for group g0 = kt*16 + w*4, this lane
        const ushort* akt = vthp
            + ((size_t)(kt * 16 + w * 4) * 8 * 64 + lane) * 8;

        #pragma unroll 2
        for (int dt = 0; dt < 8; ++dt) {
            bf16x8 af[4], bfr[4];
            #pragma unroll
            for (int mi = 0; mi < 4; ++mi)
                af[mi] = *(const bf16x8*)(akt + mi * 4096 + dt * 512);
            #pragma unroll
            for (int nj = 0; nj < 4; ++nj)
                bfr[nj] = *(const bf16x8*)&Bk[((dt * 4 + quad) * 64 + nj * 16 + l15) * 8];
            #pragma unroll
            for (int mi = 0; mi < 4; ++mi)
                #pragma unroll
                for (int nj = 0; nj < 4; ++nj)
                    acc[mi][nj] = __builtin_amdgcn_mfma_f32_16x16x32_bf16(
                        af[mi], bfr[nj], acc[mi][nj], 0, 0, 0);
        }

        // ---- fold: score = cref[k] - 2*dot; branchless packed top-2 ----
        const uint ktb = (uint)(kt << 4);
        float4 cv[4];
        #pragma unroll
        for (int mi = 0; mi < 4; ++mi)
            cv[mi] = *(const float4*)&cref[kt * 256 + w * 64 + mi * 16 + quad * 4];

        #pragma unroll
        for (int nj = 0; nj < 4; ++nj) {
            #pragma unroll
            for (int mi = 0; mi < 4; ++mi) {
                #pragma unroll
                for (int r = 0; r < 4; ++r) {
                    float s = fmaf(-2.f, acc[mi][nj][r], (&cv[mi].x)[r]);
                    uint  pk = (__float_as_uint(s) & 0xFFFFFF00u)
                             | (ktb + (uint)(mi * 4 + r));
                    float f = __uint_as_float(pk);
                    m1[nj] = __builtin_amdgcn_fmed3f(f, m0[nj], m1[nj]);
                    m0[nj] = fminf(m0[nj], f);
                }
            }
        }
    }

    // decode ids -> global k, expand to top-4, butterfly-merge across quads
    float mv[4][4];
    int   mi_[4][4];
    #pragma unroll
    for (int nj = 0; nj < 4; ++nj) {
        uint b0 = __float_as_uint(m0[nj]);
        uint b1 = __float_as_uint(m1[nj]);
        int id0 = (int)(b0 & 255u);
        int id1 = (int)(b1 & 255u);
        mv[nj][0] = m0[nj];
        mi_[nj][0] = ((id0 >> 4) << 8) + w * 64 + (((id0 >> 2) & 3) << 4)
                   + (quad << 2) + (id0 & 3);
        mv[nj][1] = m1[nj];
        mi_[nj][1] = ((id1 >> 4) << 8) + w * 64 + (((id1 >> 2) & 3) << 4)
                   + (quad << 2) + (id1 & 3);
        mv[nj][2] = FLT_MAX; mi_[nj][2] = 0;
        mv[nj][3] = FLT_MAX; mi_[nj][3] = 0;
    }
    #pragma unroll
    for (int off = 16; off <= 32; off <<= 1) {
        #pragma unroll
        for (int nj = 0; nj < 4; ++nj) {
            float ov[4]; int oi[4];
            #pragma unroll
            for (int s = 0; s < 4; ++s) {
                ov[s] = __shfl_xor(mv[nj][s], off);
                oi[s] = __shfl_xor(mi_[nj][s], off);
            }
            #pragma unroll
            for (int s = 0; s < 4; ++s)
                insert4b(mv[nj], mi_[nj], ov[s], oi[s]);
        }
    }

    __syncthreads();                    // all waves done reading Bk
    float2* mbuf = (float2*)Bk;         // overlay merge buffer on Bk
    if (quad == 0) {
        #pragma unroll
        for (int nj = 0; nj < 4; ++nj) {
            int row_local = nj * 16 + l15;
            #pragma unroll
            for (int s = 0; s < 4; ++s)
                mbuf[row_local * 16 + w * 4 + s] =
                    make_float2(mv[nj][s], __int_as_float(mi_[nj][s]));
        }
    }
    __syncthreads();
    if (tid < 64) {
        float bv[4] = {FLT_MAX, FLT_MAX, FLT_MAX, FLT_MAX};
        int   bi[4] = {0, 0, 0, 0};
        #pragma unroll
        for (int j = 0; j < 16; ++j) {
            float2 p = mbuf[tid * 16 + j];
            insert4b(bv, bi, p.x, __float_as_int(p.y));
        }
        cand[row0 + tid] = make_int4(bi[0], bi[1], bi[2], bi[3]);
    }
}

// ---------- kernel 3: LDS-staged exact rescore + select + quant + loss --------
// Per wave: 64 lanes = 16 rows x 4 cands.  The 64 candidate rows are staged
// quarter-by-quarter (64 dims) into a wave-private 16 KB LDS region with
// COALESCED loads (16 lanes per row-quarter -> 16 line-req/instr instead of 64
// scattered), XOR-swizzled so staging writes and per-lane sequential reads are
// both 2-lanes/bank (free).  The per-thread numpy-fp32 arithmetic is verbatim.
// Phase 2 fuses the old quant kernel with full-wave coalesced 1KB accesses.
__global__ __launch_bounds__(256) void vq_emuquant_kernel(
        const float* __restrict__ x, const float* __restrict__ vt,
        const float* __restrict__ cref, const int4* __restrict__ cand,
        float* __restrict__ out_q, float* __restrict__ out_idx,
        float* __restrict__ partial) {
    __shared__ __align__(16) float stage[4][4096];    // 64 KB, wave-private 16 KB

    const int tid  = threadIdx.x;
    const int w    = tid >> 6;
    const int lane = tid & 63;
    const int gid  = blockIdx.x * 256 + tid;
    const int row  = gid >> 2;
    const int cl   = gid & 3;

    float* stW = stage[w];
    float* myBase = stW + lane * 64;     // this lane's cand (slot j == lane)
    const int swz = lane & 31;

    const int c_mine = ((const int*)cand)[gid];
    const int* cbase = (const int*)cand + blockIdx.x * 256 + w * 64;

    const float4* xr = (const float4*)(x + (size_t)row * DIM);

    float b = 0.f;                       // sgemm FMA accumulator, d ascending
    float A_half[2];
    #pragma unroll
    for (int h = 0; h < 2; ++h) {
        float r[8];
        #pragma unroll
        for (int iq = 0; iq < 2; ++iq) {
            const int qq = h * 2 + iq;
            // ---- stage quarter qq: 64 cand rows x 64 dims, coalesced ----
            asm volatile("s_waitcnt lgkmcnt(0)" ::: "memory");  // WAR vs prior reads
            #pragma unroll
            for (int it = 0; it < 16; ++it) {
                int j  = it * 4 + (lane >> 4);
                int cj = cbase[j];                       // L1-hot after 1st quarter
                float4 vv = *(const float4*)(vt + (size_t)cj * DIM
                                             + qq * 64 + (lane & 15) * 4);
                int f0 = (lane & 15) * 4;
                int jx = j & 31;
                float* dst = stW + j * 64;
                dst[(f0 + 0) ^ jx] = vv.x;
                dst[(f0 + 1) ^ jx] = vv.y;
                dst[(f0 + 2) ^ jx] = vv.z;
                dst[(f0 + 3) ^ jx] = vv.w;
            }
            asm volatile("s_waitcnt lgkmcnt(0)" ::: "memory");  // RAW: writes visible
            // ---- compute the 8 i-steps of this quarter (order preserved) ----
            #pragma unroll
            for (int il = 0; il < 8; ++il) {
                const int i = iq * 8 + il;
                float4 xa = xr[h * 32 + i * 2];
                float4 xb = xr[h * 32 + i * 2 + 1];
                float xs[8] = {xa.x, xa.y, xa.z, xa.w, xb.x, xb.y, xb.z, xb.w};
                float vs[8];
                #pragma unroll
                for (int jj = 0; jj < 8; ++jj)
                    vs[jj] = myBase[(il * 8 + jj) ^ swz];
                if (i == 0) {
                    #pragma unroll
                    for (int jj = 0; jj < 8; ++jj) {
                        r[jj] = opaque(xs[jj] * xs[jj]);
                        b = fmaf(2.f * xs[jj], vs[jj], b);
                    }
                } else {
                    #pragma unroll
                    for (int jj = 0; jj < 8; ++jj) {
                        r[jj] = r[jj] + opaque(xs[jj] * xs[jj]);
                        b = fmaf(2.f * xs[jj], vs[jj], b);
                    }
                }
            }
        }
        A_half[h] = ((r[0] + r[1]) + (r[2] + r[3])) + ((r[4] + r[5]) + (r[6] + r[7]));
    }
    float A = A_half[0] + A_half[1];

    float bd = (A - b) + cref[c_mine];
    int   bk = c_mine;
    #pragma unroll
    for (int off = 1; off <= 2; off <<= 1) {
        float ov = __shfl_xor(bd, off);
        int   oi = __shfl_xor(bk, off);
        if (better(ov, oi, bd, bk)) { bd = ov; bk = oi; }
    }
    if (cl == 0) out_idx[row] = (float)bk;

    // ---- phase 2: quant + loss, one row per wave-iteration, coalesced ----
    float lsum = 0.f;
    const int wrow0 = blockIdx.x * 64 + w * 16;
    #pragma unroll 4
    for (int rr = 0; rr < 16; ++rr) {
        int kwin = __shfl(bk, rr * 4);   // uniform index -> readlane
        const float* xs = x     + (size_t)(wrow0 + rr) * DIM + lane * 4;
        const float* vs = vt    + (size_t)kwin * DIM + lane * 4;
        float*       qs = out_q + (size_t)(wrow0 + rr) * DIM + lane * 4;
        float4 xv = *(const float4*)xs;
        float4 qv = *(const float4*)vs;
        *(float4*)qs = qv;
        float dx = xv.x - qv.x, dy = xv.y - qv.y;
        float dz = xv.z - qv.z, dw2 = xv.w - qv.w;
        lsum += dx * dx + dy * dy + dz * dz + dw2 * dw2;
    }
    #pragma unroll
    for (int off = 32; off > 0; off >>= 1)
        lsum += __shfl_xor(lsum, off);
    if (lane == 0) stW[0] = lsum;        // own region start -- no cross-wave race
    __syncthreads();
    if (tid == 0)
        partial[blockIdx.x] = (stage[0][0] + stage[1][0])
                            + (stage[2][0] + stage[3][0]);
}

// ---------- kernel 5: reduce partials, finalize losses -------------------------
__global__ void vq_finalize_kernel(const float* __restrict__ partial,
                                   float* __restrict__ out_loss) {
    __shared__ double sd[256];
    double s = 0.0;
    for (int i = threadIdx.x; i < 1024; i += 256)
        s += (double)partial[i];
    sd[threadIdx.x] = s;
    __syncthreads();
    for (int off = 128; off > 0; off >>= 1) {
        if (threadIdx.x < off) sd[threadIdx.x] += sd[threadIdx.x + off];
        __syncthreads();
    }
    if (threadIdx.x == 0) {
        double m = sd[0] / (double)((long long)NROWS * DIM);
        out_loss[0] = (float)m;   // dictionary_loss
        out_loss[1] = (float)m;   // commitment_loss (identical forward value)
    }
}

extern "C" void kernel_launch(void* const* d_in, const int* in_sizes, int n_in,
                              void* d_out, int out_size, void* d_ws, size_t ws_size,
                              hipStream_t stream) {
    const float* x = (const float*)d_in[0];   // (64,1024,256)
    const float* v = (const float*)d_in[1];   // (256,4096)

    float* out      = (float*)d_out;
    float* out_q    = out;
    float* out_loss = out + (size_t)NROWS * DIM;
    float* out_idx  = out + (size_t)NROWS * DIM + 2;

    char*   ws      = (char*)d_ws;
    float*  cref    = (float*)ws;
    int4*   cand    = (int4*)(ws + 32768);
    float*  partial = (float*)(ws + 1081344);
    float*  vt      = (float*)(ws + 1343488);
    ushort* vthp    = (ushort*)(ws + 5537792);

    vq_cref_kernel<<<KCB / 256, 256, 0, stream>>>(v, cref);
    vq_transpose_kernel<<<dim3(DIM / 32, KCB / 32), dim3(32, 8), 0, stream>>>(v, vt);
    vq_pack_kernel<<<512, 256, 0, stream>>>(vt, vthp);
    vq_mfma_argmin_kernel<<<NROWS / 64, 256, 0, stream>>>(x, vthp, cref, cand);
    vq_emuquant_kernel<<<NROWS * 4 / 256, 256, 0, stream>>>(x, vt, cref, cand,
                                                            out_q, out_idx, partial);
    vq_finalize_kernel<<<1, 256, 0, stream>>>(partial, out_loss);
}

// Round 11
// 401.717 us; speedup vs baseline: 1.1789x; 1.1789x over previous
//
#include <hip/hip_runtime.h>
#include <cfloat>

#define NROWS 65536
#define DIM   256
#define KCB   4096

typedef __attribute__((ext_vector_type(8))) short bf16x8;
typedef __attribute__((ext_vector_type(4))) float f32x4;
typedef unsigned short ushort;
typedef unsigned int uint;

// ws layout (bytes):
//   [0,       16384)   : cref    float[4096]    (numpy-exact column sums of v^2)
//   [32768,   1081344) : int4    cand[65536]    (.x..z top cands, .w = chosen)
//   [1081344, 1146880) : float   partial[16384] (per-quant-block loss partials)
//   [1343488, 5537792) : vt      float[4096*256]  (transposed codebook, fp32)
//   [5537792, 7634944) : vthp    ushort[4096*256] (codebook, MFMA-fragment-packed bf16)

__device__ __forceinline__ bool better(float v1, int i1, float v2, int i2) {
    return (v1 < v2) || (v1 == v2 && i1 < i2);
}

// launder through a VGPR so hipcc cannot FMA-contract or reassociate
__device__ __forceinline__ float opaque(float x) {
    asm volatile("" : "+v"(x));
    return x;
}

__device__ __forceinline__ ushort f2bf(float f) {   // RNE fp32 -> bf16
    uint u = __float_as_uint(f);
    return (ushort)((u + 0x7FFFu + ((u >> 16) & 1u)) >> 16);
}

// lexicographic top-4 insert (for merges)
__device__ __forceinline__ void insert4b(float v[4], int idx[4], float s, int k) {
    if (better(s, k, v[3], idx[3])) {
        if (better(s, k, v[2], idx[2])) {
            v[3] = v[2]; idx[3] = idx[2];
            if (better(s, k, v[1], idx[1])) {
                v[2] = v[1]; idx[2] = idx[1];
                if (better(s, k, v[0], idx[0])) {
                    v[1] = v[0]; idx[1] = idx[0]; v[0] = s; idx[0] = k;
                } else { v[1] = s; idx[1] = k; }
            } else { v[2] = s; idx[2] = k; }
        } else { v[3] = s; idx[3] = k; }
    }
}

// ---------- kernel 1a: numpy-exact C_k = sequential sum_d fl(v[d][k]^2) --------
__global__ void vq_cref_kernel(const float* __restrict__ v,
                               float* __restrict__ cref) {
    int k = blockIdx.x * blockDim.x + threadIdx.x;
    float t = v[k];
    float c = opaque(t * t);
    #pragma unroll 8
    for (int d = 1; d < DIM; ++d) {
        t = v[d * KCB + k];
        c = c + opaque(t * t);
    }
    cref[k] = c;
}

// ---------- kernel 1b: transpose V (D,K) -> vt fp32 (K,D) ---------------------
__global__ void vq_transpose_kernel(const float* __restrict__ v,
                                    float* __restrict__ vt) {
    __shared__ float tile[32][33];
    int d0 = blockIdx.x * 32;
    int k0 = blockIdx.y * 32;
    int tx = threadIdx.x;
    int ty = threadIdx.y;
    #pragma unroll
    for (int i = 0; i < 32; i += 8)
        tile[ty + i][tx] = v[(d0 + ty + i) * KCB + k0 + tx];
    __syncthreads();
    #pragma unroll
    for (int i = 0; i < 32; i += 8)
        vt[(k0 + ty + i) * DIM + d0 + tx] = tile[tx][ty + i];
}

// ---------- kernel 1c: pack vt -> vthp in MFMA-fragment order ------------------
// Fragment f = (g*8 + dt)*64 + lane  holds bf16x8 = row (g*16 + (lane&15)),
// dims [(dt*4 + (lane>>4))*8, +8).  af loads become contiguous 1 KB bursts.
__global__ __launch_bounds__(256) void vq_pack_kernel(const float* __restrict__ vt,
                                                      ushort* __restrict__ vthp) {
    int t = blockIdx.x * 256 + threadIdx.x;   // 0..131071
    int lane = t & 63;
    int dt   = (t >> 6) & 7;
    int g    = t >> 9;                        // row-group 0..255
    int row  = g * 16 + (lane & 15);
    int dbase = (dt * 4 + (lane >> 4)) * 8;
    const float* src = vt + (size_t)row * DIM + dbase;
    float4 f0 = *(const float4*)src;
    float4 f1 = *(const float4*)(src + 4);
    int4 p;
    p.x = (int)f2bf(f0.x) | ((int)f2bf(f0.y) << 16);
    p.y = (int)f2bf(f0.z) | ((int)f2bf(f0.w) << 16);
    p.z = (int)f2bf(f1.x) | ((int)f2bf(f1.y) << 16);
    p.w = (int)f2bf(f1.z) | ((int)f2bf(f1.w) << 16);
    *(int4*)(vthp + (size_t)t * 8) = p;
}

// ---------- kernel 2: bf16 MFMA + branchless packed top-2 argmin ---------------
// Measured-optimal config: 64 rows/block, 4 blocks/CU, fragment-packed af.
__global__ __launch_bounds__(256, 4) void vq_mfma_argmin_kernel(
        const float* __restrict__ x, const ushort* __restrict__ vthp,
        const float* __restrict__ cref, int4* __restrict__ cand) {
    // Bk[u][r][8]: unit u = 8 bf16 of dims [u*8,u*8+8), r = x-row; reused as mbuf
    __shared__ __align__(16) ushort Bk[32 * 64 * 8];      // 32 KB

    const int tid  = threadIdx.x;
    const int w    = tid >> 6;        // wave 0..3
    const int lane = tid & 63;
    const int l15  = lane & 15;
    const int quad = lane >> 4;
    const int row0 = blockIdx.x * 64;

    // ---- stage x-tile once: 64 rows x 256 dims -> bf16, k-major ----
    {
        const int r_ = tid >> 2;
        const int q_ = tid & 3;
        const float* xs = &x[(size_t)(row0 + r_) * DIM + q_ * 64];
        #pragma unroll
        for (int i = 0; i < 8; ++i) {
            float4 f0 = *(const float4*)(xs + i * 8);
            float4 f1 = *(const float4*)(xs + i * 8 + 4);
            int4 p;
            p.x = (int)f2bf(f0.x) | ((int)f2bf(f0.y) << 16);
            p.y = (int)f2bf(f0.z) | ((int)f2bf(f0.w) << 16);
            p.z = (int)f2bf(f1.x) | ((int)f2bf(f1.y) << 16);
            p.w = (int)f2bf(f1.z) | ((int)f2bf(f1.w) << 16);
            int u = q_ * 8 + i;
            *(int4*)&Bk[(u * 64 + r_) * 8] = p;
        }
    }
    __syncthreads();

    // per-lane packed top-2 per nj: score with 8-bit local id in mantissa LSBs
    float m0[4], m1[4];
    #pragma unroll
    for (int nj = 0; nj < 4; ++nj) { m0[nj] = FLT_MAX; m1[nj] = FLT_MAX; }

    for (int kt = 0; kt < 16; ++kt) {
        f32x4 acc[4][4];
        #pragma unroll
        for (int mi = 0; mi < 4; ++mi)
            #pragma unroll
            for (int nj = 0; nj < 4; ++nj)
                acc[mi][nj] = (f32x4)0.f;

        // fragment base for group g0 = kt*16 + w*4, this lane
        const ushort* akt = vthp
            + ((size_t)(kt * 16 + w * 4) * 8 * 64 + lane) * 8;

        #pragma unroll 2
        for (int dt = 0; dt < 8; ++dt) {
            bf16x8 af[4], bfr[4];
            #pragma unroll
            for (int mi = 0; mi < 4; ++mi)
                af[mi] = *(const bf16x8*)(akt + mi * 4096 + dt * 512);
            #pragma unroll
            for (int nj = 0; nj < 4; ++nj)
                bfr[nj] = *(const bf16x8*)&Bk[((dt * 4 + quad) * 64 + nj * 16 + l15) * 8];
            #pragma unroll
            for (int mi = 0; mi < 4; ++mi)
                #pragma unroll
                for (int nj = 0; nj < 4; ++nj)
                    acc[mi][nj] = __builtin_amdgcn_mfma_f32_16x16x32_bf16(
                        af[mi], bfr[nj], acc[mi][nj], 0, 0, 0);
        }

        // ---- fold: score = cref[k] - 2*dot; branchless packed top-2 ----
        const uint ktb = (uint)(kt << 4);
        float4 cv[4];
        #pragma unroll
        for (int mi = 0; mi < 4; ++mi)
            cv[mi] = *(const float4*)&cref[kt * 256 + w * 64 + mi * 16 + quad * 4];

        #pragma unroll
        for (int nj = 0; nj < 4; ++nj) {
            #pragma unroll
            for (int mi = 0; mi < 4; ++mi) {
                #pragma unroll
                for (int r = 0; r < 4; ++r) {
                    float s = fmaf(-2.f, acc[mi][nj][r], (&cv[mi].x)[r]);
                    uint  pk = (__float_as_uint(s) & 0xFFFFFF00u)
                             | (ktb + (uint)(mi * 4 + r));
                    float f = __uint_as_float(pk);
                    m1[nj] = __builtin_amdgcn_fmed3f(f, m0[nj], m1[nj]);
                    m0[nj] = fminf(m0[nj], f);
                }
            }
        }
    }

    // decode ids -> global k, expand to top-4, butterfly-merge across quads
    float mv[4][4];
    int   mi_[4][4];
    #pragma unroll
    for (int nj = 0; nj < 4; ++nj) {
        uint b0 = __float_as_uint(m0[nj]);
        uint b1 = __float_as_uint(m1[nj]);
        int id0 = (int)(b0 & 255u);
        int id1 = (int)(b1 & 255u);
        mv[nj][0] = m0[nj];
        mi_[nj][0] = ((id0 >> 4) << 8) + w * 64 + (((id0 >> 2) & 3) << 4)
                   + (quad << 2) + (id0 & 3);
        mv[nj][1] = m1[nj];
        mi_[nj][1] = ((id1 >> 4) << 8) + w * 64 + (((id1 >> 2) & 3) << 4)
                   + (quad << 2) + (id1 & 3);
        mv[nj][2] = FLT_MAX; mi_[nj][2] = 0;
        mv[nj][3] = FLT_MAX; mi_[nj][3] = 0;
    }
    #pragma unroll
    for (int off = 16; off <= 32; off <<= 1) {
        #pragma unroll
        for (int nj = 0; nj < 4; ++nj) {
            float ov[4]; int oi[4];
            #pragma unroll
            for (int s = 0; s < 4; ++s) {
                ov[s] = __shfl_xor(mv[nj][s], off);
                oi[s] = __shfl_xor(mi_[nj][s], off);
            }
            #pragma unroll
            for (int s = 0; s < 4; ++s)
                insert4b(mv[nj], mi_[nj], ov[s], oi[s]);
        }
    }

    __syncthreads();                    // all waves done reading Bk
    float2* mbuf = (float2*)Bk;         // overlay merge buffer on Bk
    if (quad == 0) {
        #pragma unroll
        for (int nj = 0; nj < 4; ++nj) {
            int row_local = nj * 16 + l15;
            #pragma unroll
            for (int s = 0; s < 4; ++s)
                mbuf[row_local * 16 + w * 4 + s] =
                    make_float2(mv[nj][s], __int_as_float(mi_[nj][s]));
        }
    }
    __syncthreads();
    if (tid < 64) {
        float bv[4] = {FLT_MAX, FLT_MAX, FLT_MAX, FLT_MAX};
        int   bi[4] = {0, 0, 0, 0};
        #pragma unroll
        for (int j = 0; j < 16; ++j) {
            float2 p = mbuf[tid * 16 + j];
            insert4b(bv, bi, p.x, __float_as_int(p.y));
        }
        cand[row0 + tid] = make_int4(bi[0], bi[1], bi[2], bi[3]);
    }
}

// ---------- kernel 3: numpy-fp32 bit-exact re-score of top-4, select ----------
// ONE thread per row, 4 candidates serial in-thread: A (x^2 chain) computed
// once instead of 4x, x loads not 4x-redundant, and the 4 independent b-chains
// interleave for ILP.  Each per-candidate fmaf chain is bit-identical to the
// old 4-thread version; winner = lexicographic min (order-independent).
__global__ __launch_bounds__(256) void vq_emulate_kernel(
        const float* __restrict__ x, const float* __restrict__ vt,
        const float* __restrict__ cref, int4* __restrict__ cand,
        float* __restrict__ out_idx) {
    int row = blockIdx.x * 256 + threadIdx.x;
    int4 c4 = cand[row];
    int ci[4] = {c4.x, c4.y, c4.z, c4.w};

    const float4* xr = (const float4*)(x + (size_t)row * DIM);
    const float4* vr[4] = {
        (const float4*)(vt + (size_t)c4.x * DIM),
        (const float4*)(vt + (size_t)c4.y * DIM),
        (const float4*)(vt + (size_t)c4.z * DIM),
        (const float4*)(vt + (size_t)c4.w * DIM) };

    float b[4] = {0.f, 0.f, 0.f, 0.f};   // 4 independent d-ascending fmaf chains
    float A_half[2];
    #pragma unroll
    for (int h = 0; h < 2; ++h) {
        float r[8];
        #pragma unroll 4
        for (int i = 0; i < 16; ++i) {
            float4 xa = xr[h * 32 + i * 2];
            float4 xb = xr[h * 32 + i * 2 + 1];
            float xs[8] = {xa.x, xa.y, xa.z, xa.w, xb.x, xb.y, xb.z, xb.w};
            float vs[4][8];
            #pragma unroll
            for (int k = 0; k < 4; ++k) {
                float4 va = vr[k][h * 32 + i * 2];
                float4 vb = vr[k][h * 32 + i * 2 + 1];
                vs[k][0] = va.x; vs[k][1] = va.y; vs[k][2] = va.z; vs[k][3] = va.w;
                vs[k][4] = vb.x; vs[k][5] = vb.y; vs[k][6] = vb.z; vs[k][7] = vb.w;
            }
            if (i == 0) {
                #pragma unroll
                for (int j = 0; j < 8; ++j)
                    r[j] = opaque(xs[j] * xs[j]);
            } else {
                #pragma unroll
                for (int j = 0; j < 8; ++j)
                    r[j] = r[j] + opaque(xs[j] * xs[j]);
            }
            #pragma unroll
            for (int k = 0; k < 4; ++k)
                #pragma unroll
                for (int j = 0; j < 8; ++j)
                    b[k] = fmaf(2.f * xs[j], vs[k][j], b[k]);
        }
        A_half[h] = ((r[0] + r[1]) + (r[2] + r[3])) + ((r[4] + r[5]) + (r[6] + r[7]));
    }
    float A = A_half[0] + A_half[1];

    float bd = (A - b[0]) + cref[ci[0]];
    int   bk = ci[0];
    #pragma unroll
    for (int k = 1; k < 4; ++k) {
        float dk = (A - b[k]) + cref[ci[k]];
        if (better(dk, ci[k], bd, bk)) { bd = dk; bk = ci[k]; }
    }
    ((int*)(cand + row))[3] = bk;
    out_idx[row] = (float)bk;
}

// ---------- kernel 4: gather chosen vector, write out_q, loss partial ----------
// 64 lanes per row: contiguous 1 KB wave-loads/stores (coalesced).
__global__ __launch_bounds__(256) void vq_quant_kernel(
        const float* __restrict__ x, const float* __restrict__ vt,
        const int4* __restrict__ cand, float* __restrict__ out_q,
        float* __restrict__ partial) {
    const int tid    = threadIdx.x;
    const int rlocal = tid >> 6;
    const int lane   = tid & 63;
    const int row    = blockIdx.x * 4 + rlocal;
    const int k      = ((const int*)(cand + row))[3];

    float4 xv = *(const float4*)&x[(size_t)row * DIM + lane * 4];
    float4 q  = *(const float4*)&vt[(size_t)k * DIM + lane * 4];
    *(float4*)&out_q[(size_t)row * DIM + lane * 4] = q;

    float dx = xv.x - q.x, dy = xv.y - q.y, dz = xv.z - q.z, dw = xv.w - q.w;
    float sum = dx * dx + dy * dy + dz * dz + dw * dw;
    #pragma unroll
    for (int off = 32; off > 0; off >>= 1)
        sum += __shfl_xor(sum, off);

    __shared__ float bsum[4];
    if (lane == 0) bsum[rlocal] = sum;
    __syncthreads();
    if (tid == 0)
        partial[blockIdx.x] = bsum[0] + bsum[1] + bsum[2] + bsum[3];
}

// ---------- kernel 5: reduce partials, finalize losses -------------------------
__global__ void vq_finalize_kernel(const float* __restrict__ partial,
                                   float* __restrict__ out_loss) {
    __shared__ double sd[256];
    double s = 0.0;
    for (int i = threadIdx.x; i < NROWS / 4; i += 256)
        s += (double)partial[i];
    sd[threadIdx.x] = s;
    __syncthreads();
    for (int off = 128; off > 0; off >>= 1) {
        if (threadIdx.x < off) sd[threadIdx.x] += sd[threadIdx.x + off];
        __syncthreads();
    }
    if (threadIdx.x == 0) {
        double m = sd[0] / (double)((long long)NROWS * DIM);
        out_loss[0] = (float)m;   // dictionary_loss
        out_loss[1] = (float)m;   // commitment_loss (identical forward value)
    }
}

extern "C" void kernel_launch(void* const* d_in, const int* in_sizes, int n_in,
                              void* d_out, int out_size, void* d_ws, size_t ws_size,
                              hipStream_t stream) {
    const float* x = (const float*)d_in[0];   // (64,1024,256)
    const float* v = (const float*)d_in[1];   // (256,4096)

    float* out      = (float*)d_out;
    float* out_q    = out;
    float* out_loss = out + (size_t)NROWS * DIM;
    float* out_idx  = out + (size_t)NROWS * DIM + 2;

    char*   ws      = (char*)d_ws;
    float*  cref    = (float*)ws;
    int4*   cand    = (int4*)(ws + 32768);
    float*  partial = (float*)(ws + 1081344);
    float*  vt      = (float*)(ws + 1343488);
    ushort* vthp    = (ushort*)(ws + 5537792);

    vq_cref_kernel<<<KCB / 256, 256, 0, stream>>>(v, cref);
    vq_transpose_kernel<<<dim3(DIM / 32, KCB / 32), dim3(32, 8), 0, stream>>>(v, vt);
    vq_pack_kernel<<<512, 256, 0, stream>>>(vt, vthp);
    vq_mfma_argmin_kernel<<<NROWS / 64, 256, 0, stream>>>(x, vthp, cref, cand);
    vq_emulate_kernel<<<NROWS / 256, 256, 0, stream>>>(x, vt, cref, cand, out_idx);
    vq_quant_kernel<<<NROWS / 4, 256, 0, stream>>>(x, vt, cand, out_q, partial);
    vq_finalize_kernel<<<1, 256, 0, stream>>>(partial, out_loss);
}

// Round 12
// 385.793 us; speedup vs baseline: 1.2276x; 1.0413x over previous
//
#include <hip/hip_runtime.h>
#include <cfloat>

#define NROWS 65536
#define DIM   256
#define KCB   4096

typedef __attribute__((ext_vector_type(8))) short bf16x8;
typedef __attribute__((ext_vector_type(4))) float f32x4;
typedef unsigned short ushort;
typedef unsigned int uint;

// ws layout (bytes):
//   [0,       16384)   : cref    float[4096]    (numpy-exact column sums of v^2)
//   [32768,   1081344) : int4    cand[65536]    (top-4 candidates per row)
//   [1081344, 1146880) : float   partial[1024]  (per-emuquant-block loss partials)
//   [1343488, 5537792) : vt      float[4096*256]  (transposed codebook, fp32)
//   [5537792, 7634944) : vthp    ushort[4096*256] (codebook, MFMA-fragment-packed bf16)

__device__ __forceinline__ bool better(float v1, int i1, float v2, int i2) {
    return (v1 < v2) || (v1 == v2 && i1 < i2);
}

// launder through a VGPR so hipcc cannot FMA-contract or reassociate
__device__ __forceinline__ float opaque(float x) {
    asm volatile("" : "+v"(x));
    return x;
}

__device__ __forceinline__ ushort f2bf(float f) {   // RNE fp32 -> bf16
    uint u = __float_as_uint(f);
    return (ushort)((u + 0x7FFFu + ((u >> 16) & 1u)) >> 16);
}

// lexicographic top-4 insert (for merges)
__device__ __forceinline__ void insert4b(float v[4], int idx[4], float s, int k) {
    if (better(s, k, v[3], idx[3])) {
        if (better(s, k, v[2], idx[2])) {
            v[3] = v[2]; idx[3] = idx[2];
            if (better(s, k, v[1], idx[1])) {
                v[2] = v[1]; idx[2] = idx[1];
                if (better(s, k, v[0], idx[0])) {
                    v[1] = v[0]; idx[1] = idx[0]; v[0] = s; idx[0] = k;
                } else { v[1] = s; idx[1] = k; }
            } else { v[2] = s; idx[2] = k; }
        } else { v[3] = s; idx[3] = k; }
    }
}

// ---------- kernel 1a: numpy-exact C_k = sequential sum_d fl(v[d][k]^2) --------
__global__ void vq_cref_kernel(const float* __restrict__ v,
                               float* __restrict__ cref) {
    int k = blockIdx.x * blockDim.x + threadIdx.x;
    float t = v[k];
    float c = opaque(t * t);
    #pragma unroll 8
    for (int d = 1; d < DIM; ++d) {
        t = v[d * KCB + k];
        c = c + opaque(t * t);
    }
    cref[k] = c;
}

// ---------- kernel 1b: transpose V (D,K) -> vt fp32 (K,D) ---------------------
__global__ void vq_transpose_kernel(const float* __restrict__ v,
                                    float* __restrict__ vt) {
    __shared__ float tile[32][33];
    int d0 = blockIdx.x * 32;
    int k0 = blockIdx.y * 32;
    int tx = threadIdx.x;
    int ty = threadIdx.y;
    #pragma unroll
    for (int i = 0; i < 32; i += 8)
        tile[ty + i][tx] = v[(d0 + ty + i) * KCB + k0 + tx];
    __syncthreads();
    #pragma unroll
    for (int i = 0; i < 32; i += 8)
        vt[(k0 + ty + i) * DIM + d0 + tx] = tile[tx][ty + i];
}

// ---------- kernel 1c: pack vt -> vthp in MFMA-fragment order ------------------
// Fragment f = (g*8 + dt)*64 + lane  holds bf16x8 = row (g*16 + (lane&15)),
// dims [(dt*4 + (lane>>4))*8, +8).  af loads become contiguous 1 KB bursts.
__global__ __launch_bounds__(256) void vq_pack_kernel(const float* __restrict__ vt,
                                                      ushort* __restrict__ vthp) {
    int t = blockIdx.x * 256 + threadIdx.x;   // 0..131071
    int lane = t & 63;
    int dt   = (t >> 6) & 7;
    int g    = t >> 9;                        // row-group 0..255
    int row  = g * 16 + (lane & 15);
    int dbase = (dt * 4 + (lane >> 4)) * 8;
    const float* src = vt + (size_t)row * DIM + dbase;
    float4 f0 = *(const float4*)src;
    float4 f1 = *(const float4*)(src + 4);
    int4 p;
    p.x = (int)f2bf(f0.x) | ((int)f2bf(f0.y) << 16);
    p.y = (int)f2bf(f0.z) | ((int)f2bf(f0.w) << 16);
    p.z = (int)f2bf(f1.x) | ((int)f2bf(f1.y) << 16);
    p.w = (int)f2bf(f1.z) | ((int)f2bf(f1.w) << 16);
    *(int4*)(vthp + (size_t)t * 8) = p;
}

// ---------- kernel 2: bf16 MFMA + branchless packed top-2 argmin ---------------
// Measured-optimal config: 64 rows/block, 4 blocks/CU, fragment-packed af.
__global__ __launch_bounds__(256, 4) void vq_mfma_argmin_kernel(
        const float* __restrict__ x, const ushort* __restrict__ vthp,
        const float* __restrict__ cref, int4* __restrict__ cand) {
    // Bk[u][r][8]: unit u = 8 bf16 of dims [u*8,u*8+8), r = x-row; reused as mbuf
    __shared__ __align__(16) ushort Bk[32 * 64 * 8];      // 32 KB

    const int tid  = threadIdx.x;
    const int w    = tid >> 6;        // wave 0..3
    const int lane = tid & 63;
    const int l15  = lane & 15;
    const int quad = lane >> 4;
    const int row0 = blockIdx.x * 64;

    // ---- stage x-tile once: 64 rows x 256 dims -> bf16, k-major ----
    {
        const int r_ = tid >> 2;
        const int q_ = tid & 3;
        const float* xs = &x[(size_t)(row0 + r_) * DIM + q_ * 64];
        #pragma unroll
        for (int i = 0; i < 8; ++i) {
            float4 f0 = *(const float4*)(xs + i * 8);
            float4 f1 = *(const float4*)(xs + i * 8 + 4);
            int4 p;
            p.x = (int)f2bf(f0.x) | ((int)f2bf(f0.y) << 16);
            p.y = (int)f2bf(f0.z) | ((int)f2bf(f0.w) << 16);
            p.z = (int)f2bf(f1.x) | ((int)f2bf(f1.y) << 16);
            p.w = (int)f2bf(f1.z) | ((int)f2bf(f1.w) << 16);
            int u = q_ * 8 + i;
            *(int4*)&Bk[(u * 64 + r_) * 8] = p;
        }
    }
    __syncthreads();

    // per-lane packed top-2 per nj: score with 8-bit local id in mantissa LSBs
    float m0[4], m1[4];
    #pragma unroll
    for (int nj = 0; nj < 4; ++nj) { m0[nj] = FLT_MAX; m1[nj] = FLT_MAX; }

    for (int kt = 0; kt < 16; ++kt) {
        f32x4 acc[4][4];
        #pragma unroll
        for (int mi = 0; mi < 4; ++mi)
            #pragma unroll
            for (int nj = 0; nj < 4; ++nj)
                acc[mi][nj] = (f32x4)0.f;

        // fragment base for group g0 = kt*16 + w*4, this lane
        const ushort* akt = vthp
            + ((size_t)(kt * 16 + w * 4) * 8 * 64 + lane) * 8;

        #pragma unroll 2
        for (int dt = 0; dt < 8; ++dt) {
            bf16x8 af[4], bfr[4];
            #pragma unroll
            for (int mi = 0; mi < 4; ++mi)
                af[mi] = *(const bf16x8*)(akt + mi * 4096 + dt * 512);
            #pragma unroll
            for (int nj = 0; nj < 4; ++nj)
                bfr[nj] = *(const bf16x8*)&Bk[((dt * 4 + quad) * 64 + nj * 16 + l15) * 8];
            #pragma unroll
            for (int mi = 0; mi < 4; ++mi)
                #pragma unroll
                for (int nj = 0; nj < 4; ++nj)
                    acc[mi][nj] = __builtin_amdgcn_mfma_f32_16x16x32_bf16(
                        af[mi], bfr[nj], acc[mi][nj], 0, 0, 0);
        }

        // ---- fold: score = cref[k] - 2*dot; branchless packed top-2 ----
        const uint ktb = (uint)(kt << 4);
        float4 cv[4];
        #pragma unroll
        for (int mi = 0; mi < 4; ++mi)
            cv[mi] = *(const float4*)&cref[kt * 256 + w * 64 + mi * 16 + quad * 4];

        #pragma unroll
        for (int nj = 0; nj < 4; ++nj) {
            #pragma unroll
            for (int mi = 0; mi < 4; ++mi) {
                #pragma unroll
                for (int r = 0; r < 4; ++r) {
                    float s = fmaf(-2.f, acc[mi][nj][r], (&cv[mi].x)[r]);
                    uint  pk = (__float_as_uint(s) & 0xFFFFFF00u)
                             | (ktb + (uint)(mi * 4 + r));
                    float f = __uint_as_float(pk);
                    m1[nj] = __builtin_amdgcn_fmed3f(f, m0[nj], m1[nj]);
                    m0[nj] = fminf(m0[nj], f);
                }
            }
        }
    }

    // decode ids -> global k, expand to top-4, butterfly-merge across quads
    float mv[4][4];
    int   mi_[4][4];
    #pragma unroll
    for (int nj = 0; nj < 4; ++nj) {
        uint b0 = __float_as_uint(m0[nj]);
        uint b1 = __float_as_uint(m1[nj]);
        int id0 = (int)(b0 & 255u);
        int id1 = (int)(b1 & 255u);
        mv[nj][0] = m0[nj];
        mi_[nj][0] = ((id0 >> 4) << 8) + w * 64 + (((id0 >> 2) & 3) << 4)
                   + (quad << 2) + (id0 & 3);
        mv[nj][1] = m1[nj];
        mi_[nj][1] = ((id1 >> 4) << 8) + w * 64 + (((id1 >> 2) & 3) << 4)
                   + (quad << 2) + (id1 & 3);
        mv[nj][2] = FLT_MAX; mi_[nj][2] = 0;
        mv[nj][3] = FLT_MAX; mi_[nj][3] = 0;
    }
    #pragma unroll
    for (int off = 16; off <= 32; off <<= 1) {
        #pragma unroll
        for (int nj = 0; nj < 4; ++nj) {
            float ov[4]; int oi[4];
            #pragma unroll
            for (int s = 0; s < 4; ++s) {
                ov[s] = __shfl_xor(mv[nj][s], off);
                oi[s] = __shfl_xor(mi_[nj][s], off);
            }
            #pragma unroll
            for (int s = 0; s < 4; ++s)
                insert4b(mv[nj], mi_[nj], ov[s], oi[s]);
        }
    }

    __syncthreads();                    // all waves done reading Bk
    float2* mbuf = (float2*)Bk;         // overlay merge buffer on Bk
    if (quad == 0) {
        #pragma unroll
        for (int nj = 0; nj < 4; ++nj) {
            int row_local = nj * 16 + l15;
            #pragma unroll
            for (int s = 0; s < 4; ++s)
                mbuf[row_local * 16 + w * 4 + s] =
                    make_float2(mv[nj][s], __int_as_float(mi_[nj][s]));
        }
    }
    __syncthreads();
    if (tid < 64) {
        float bv[4] = {FLT_MAX, FLT_MAX, FLT_MAX, FLT_MAX};
        int   bi[4] = {0, 0, 0, 0};
        #pragma unroll
        for (int j = 0; j < 16; ++j) {
            float2 p = mbuf[tid * 16 + j];
            insert4b(bv, bi, p.x, __float_as_int(p.y));
        }
        cand[row0 + tid] = make_int4(bi[0], bi[1], bi[2], bi[3]);
    }
}

// ---------- kernel 3: exact rescore + select + quant + loss (merged) ----------
// Phase 1 = R7's 4-thread/row numpy-fp32 rescore VERBATIM (best measured
// variant).  Phase 2 = R8's proven-correct coalesced quant VERBATIM: wave w
// owns rows w*16..w*16+15 in BOTH phases, so the winner moves lane->lane via
// __shfl (no LDS, no barrier) and quant uses full-wave 1 KB accesses on
// L1/L2-warm x rows.  Deletes the quant launch, its 67 MB x HBM re-read, and
// the cand.w global round-trip.
__global__ __launch_bounds__(256) void vq_emuquant_kernel(
        const float* __restrict__ x, const float* __restrict__ vt,
        const float* __restrict__ cref, const int4* __restrict__ cand,
        float* __restrict__ out_q, float* __restrict__ out_idx,
        float* __restrict__ partial) {
    const int tid  = threadIdx.x;
    const int w    = tid >> 6;
    const int lane = tid & 63;
    const int gid  = blockIdx.x * 256 + tid;
    const int row  = gid >> 2;
    const int cl   = gid & 3;
    const int c    = ((const int*)cand)[gid];

    const float4* xr = (const float4*)(x + (size_t)row * DIM);
    const float4* vr = (const float4*)(vt + (size_t)c * DIM);

    float b = 0.f;                      // sgemm FMA accumulator, d ascending
    float A_half[2];
    #pragma unroll
    for (int h = 0; h < 2; ++h) {
        float r[8];
        #pragma unroll 4
        for (int i = 0; i < 16; ++i) {
            float4 xa = xr[h * 32 + i * 2];
            float4 xb = xr[h * 32 + i * 2 + 1];
            float4 va = vr[h * 32 + i * 2];
            float4 vb = vr[h * 32 + i * 2 + 1];
            float xs[8] = {xa.x, xa.y, xa.z, xa.w, xb.x, xb.y, xb.z, xb.w};
            float vs[8] = {va.x, va.y, va.z, va.w, vb.x, vb.y, vb.z, vb.w};
            if (i == 0) {
                #pragma unroll
                for (int j = 0; j < 8; ++j) {
                    r[j] = opaque(xs[j] * xs[j]);
                    b = fmaf(2.f * xs[j], vs[j], b);
                }
            } else {
                #pragma unroll
                for (int j = 0; j < 8; ++j) {
                    r[j] = r[j] + opaque(xs[j] * xs[j]);
                    b = fmaf(2.f * xs[j], vs[j], b);
                }
            }
        }
        A_half[h] = ((r[0] + r[1]) + (r[2] + r[3])) + ((r[4] + r[5]) + (r[6] + r[7]));
    }
    float A = A_half[0] + A_half[1];

    float bd = (A - b) + cref[c];
    int   bk = c;
    #pragma unroll
    for (int off = 1; off <= 2; off <<= 1) {
        float ov = __shfl_xor(bd, off);
        int   oi = __shfl_xor(bk, off);
        if (better(ov, oi, bd, bk)) { bd = ov; bk = oi; }
    }
    if (cl == 0) out_idx[row] = (float)bk;

    // ---- phase 2: quant + loss, one row per wave-iteration, coalesced ----
    float lsum = 0.f;
    const int wrow0 = blockIdx.x * 64 + w * 16;
    #pragma unroll 4
    for (int rr = 0; rr < 16; ++rr) {
        int kwin = __shfl(bk, rr * 4);   // uniform index -> readlane
        const float* xs = x     + (size_t)(wrow0 + rr) * DIM + lane * 4;
        const float* vs = vt    + (size_t)kwin * DIM + lane * 4;
        float*       qs = out_q + (size_t)(wrow0 + rr) * DIM + lane * 4;
        float4 xv = *(const float4*)xs;
        float4 qv = *(const float4*)vs;
        *(float4*)qs = qv;
        float dx = xv.x - qv.x, dy = xv.y - qv.y;
        float dz = xv.z - qv.z, dw2 = xv.w - qv.w;
        lsum += dx * dx + dy * dy + dz * dz + dw2 * dw2;
    }
    #pragma unroll
    for (int off = 32; off > 0; off >>= 1)
        lsum += __shfl_xor(lsum, off);

    __shared__ float bsum[4];
    if (lane == 0) bsum[w] = lsum;
    __syncthreads();
    if (tid == 0)
        partial[blockIdx.x] = (bsum[0] + bsum[1]) + (bsum[2] + bsum[3]);
}

// ---------- kernel 5: reduce partials, finalize losses -------------------------
__global__ void vq_finalize_kernel(const float* __restrict__ partial,
                                   float* __restrict__ out_loss) {
    __shared__ double sd[256];
    double s = 0.0;
    for (int i = threadIdx.x; i < 1024; i += 256)
        s += (double)partial[i];
    sd[threadIdx.x] = s;
    __syncthreads();
    for (int off = 128; off > 0; off >>= 1) {
        if (threadIdx.x < off) sd[threadIdx.x] += sd[threadIdx.x + off];
        __syncthreads();
    }
    if (threadIdx.x == 0) {
        double m = sd[0] / (double)((long long)NROWS * DIM);
        out_loss[0] = (float)m;   // dictionary_loss
        out_loss[1] = (float)m;   // commitment_loss (identical forward value)
    }
}

extern "C" void kernel_launch(void* const* d_in, const int* in_sizes, int n_in,
                              void* d_out, int out_size, void* d_ws, size_t ws_size,
                              hipStream_t stream) {
    const float* x = (const float*)d_in[0];   // (64,1024,256)
    const float* v = (const float*)d_in[1];   // (256,4096)

    float* out      = (float*)d_out;
    float* out_q    = out;
    float* out_loss = out + (size_t)NROWS * DIM;
    float* out_idx  = out + (size_t)NROWS * DIM + 2;

    char*   ws      = (char*)d_ws;
    float*  cref    = (float*)ws;
    int4*   cand    = (int4*)(ws + 32768);
    float*  partial = (float*)(ws + 1081344);
    float*  vt      = (float*)(ws + 1343488);
    ushort* vthp    = (ushort*)(ws + 5537792);

    vq_cref_kernel<<<KCB / 256, 256, 0, stream>>>(v, cref);
    vq_transpose_kernel<<<dim3(DIM / 32, KCB / 32), dim3(32, 8), 0, stream>>>(v, vt);
    vq_pack_kernel<<<512, 256, 0, stream>>>(vt, vthp);
    vq_mfma_argmin_kernel<<<NROWS / 64, 256, 0, stream>>>(x, vthp, cref, cand);
    vq_emuquant_kernel<<<NROWS * 4 / 256, 256, 0, stream>>>(x, vt, cref, cand,
                                                            out_q, out_idx, partial);
    vq_finalize_kernel<<<1, 256, 0, stream>>>(partial, out_loss);
}